// Round 5
// baseline (60.362 us; speedup 1.0000x reference)
//
#include <hip/hip_runtime.h>

#define NN    16384
#define CBN   64
#define SUBV  16
#define KCODE 16
#define DOUTN 1024
#define DEP   4

typedef short bf16x8 __attribute__((ext_vector_type(8)));
typedef float f32x16 __attribute__((ext_vector_type(16)));

static __device__ __forceinline__ unsigned short f2bf(float f) {
  unsigned int u = __float_as_uint(f);
  u += 0x7FFFu + ((u >> 16) & 1u);   // RNE; inputs are normal randn, no NaN/Inf
  return (unsigned short)(u >> 16);
}

// global -> LDS direct copy, 16B/lane. LDS dest wave-uniform (HW adds lane*16).
static __device__ __forceinline__ void gld16(const void* g, void* l) {
  __builtin_amdgcn_global_load_lds(
      (const __attribute__((address_space(1))) unsigned int*)g,
      (__attribute__((address_space(3))) unsigned int*)(uintptr_t)l, 16, 0, 0);
}

// ---------------- kernel 1: table convert/swizzle + encode (fused) ----------
// blocks [0,64): build Tswz (bf16, pre-swizzled 32 KiB images) — scheduled
// FIRST so they overlap encode instead of tailing it.
// blocks [64, 64+2048): encode 8 rows each -> codes[n][c] (u8, n-major).
__global__ __launch_bounds__(256) void prep_k(
    const float* __restrict__ x, const int* __restrict__ split_idxs,
    const float* __restrict__ split_vals, const float* __restrict__ Tg,
    unsigned char* __restrict__ codes, unsigned int* __restrict__ Tswz) {
  const int t = threadIdx.x;

  if (blockIdx.x < 64) {
    // ---- convert + swizzle: one block per (g8, ch) image ----
    const int img = blockIdx.x;                   // = g8*8 + ch
    const int g = img >> 3, ch = img & 7;
    unsigned int* dst = Tswz + (size_t)img * 8192; // 8192 u32 = 32 KiB image
    const int colq = t & 31, kp = (t >> 5) & 7;
    #pragma unroll
    for (int cl = 0; cl < 8; ++cl) {
      const float* g0 = Tg + ((size_t)((ch * 8 + cl) * KCODE + 2 * kp)) * DOUTN
                        + g * 128 + colq * 4;
      float4 r0 = *(const float4*)g0;             // k=2kp   (coalesced)
      float4 r1 = *(const float4*)(g0 + DOUTN);   // k=2kp+1
      unsigned int pk[4] = {
        f2bf(r0.x) | ((unsigned int)f2bf(r1.x) << 16),
        f2bf(r0.y) | ((unsigned int)f2bf(r1.y) << 16),
        f2bf(r0.z) | ((unsigned int)f2bf(r1.z) << 16),
        f2bf(r0.w) | ((unsigned int)f2bf(r1.w) << 16)};
      unsigned key = (unsigned)(colq & 7) << 2;   // XOR on u32-idx bits[4:2]
      #pragma unroll
      for (int j = 0; j < 4; ++j)
        dst[cl * 1024 + ((((unsigned)(colq * 4 + j)) * 8 + (unsigned)kp) ^ key)]
            = pk[j];
    }
    return;
  }

  // ---- encode ----
  // xs stays 32 KiB (3 blocks/CU; R3's +1-pad was 139 KiB -> 1 block/CU!).
  // Bank spread via size-neutral XOR swizzle: element s stored at s^((c>>1)&15).
  __shared__ float xs[8][SUBV * CBN];
  __shared__ int   sidxT[DEP * CBN];               // [d][c]
  __shared__ float svalT[DEP * (KCODE / 2) * CBN]; // [d][e][c]
  if (t < DEP * CBN) {
    int d = t >> 6, c = t & 63;
    sidxT[t] = split_idxs[c * DEP + d];
  }
  for (int i = t; i < DEP * (KCODE / 2) * CBN; i += 256) {
    int c = i & 63, de = i >> 6, d = de >> 3, e = de & 7;
    svalT[i] = split_vals[(c * DEP + d) * (KCODE / 2) + e];
  }
  const int n0 = (blockIdx.x - 64) * 8;
  const float4* xg = (const float4*)(x + (size_t)n0 * DOUTN);
  #pragma unroll
  for (int i = 0; i < 8; ++i) {                    // 8 rows * 256 float4/row
    int li = t + i * 256;
    int r = li >> 8, cpos = li & 255;
    float4 v = xg[r * 256 + cpos];
    int c = cpos >> 2, s0 = (cpos & 3) * 4, m = (c >> 1) & 15;
    float* row = &xs[r][c * SUBV];
    row[(s0 + 0) ^ m] = v.x; row[(s0 + 1) ^ m] = v.y;
    row[(s0 + 2) ^ m] = v.z; row[(s0 + 3) ^ m] = v.w;
  }
  __syncthreads();
  const int c = t & 63, rg = t >> 6, m = (c >> 1) & 15;
  #pragma unroll
  for (int i = 0; i < 2; ++i) {
    int nl = rg * 2 + i;
    int e = 0;
    #pragma unroll
    for (int d = 0; d < DEP; ++d) {
      float xv = xs[nl][c * SUBV + (sidxT[d * 64 + c] ^ m)];
      float th = svalT[(d * 8 + e) * 64 + c];
      e = 2 * e + (xv > th ? 1 : 0);
    }
    codes[(size_t)(n0 + nl) * CBN + c] = (unsigned char)e;
  }
}

// ---------------- kernel 2: one-hot MFMA gather-accumulate ----------------
// grid (16 colgroups of 64, 64 rowgroups) = 1024 blocks; 256 thr = 4 waves;
// 3 blocks/CU (LDS 32 KiB dbuf). Block: 256 rows x 64 cols. Wave wid:
// rh = wid&1 (128-row half), chh = wid>>1 (32-col half) -> wave = 4 row-tiles
// sharing each B-read: 1 ds_read_b128 feeds 4 MFMA. Per-chunk code loads
// issued BEFORE next-chunk gld16s so their waitcnt leaves staging in flight.
// R4 bug fixed: per-cl LDS stride in the read is 1024 u16 (2 KiB: 64 cols x
// 16 k x 2 B), not 2048 (that was the 128-col image stride) — cl>=4 was OOB.
__global__ __launch_bounds__(256, 3) void maddness_mfma(
    const unsigned int* __restrict__ Tswz, const float* __restrict__ bias,
    const unsigned char* __restrict__ codes, float* __restrict__ out) {
  __shared__ __align__(16) unsigned int Tb[2][4096];   // 2 x 16 KiB

  const int t = threadIdx.x;
  const int wid = t >> 6, lane = t & 63, lrow = lane & 31, h = lane >> 5;
  const int rh = wid & 1, chh = wid >> 1;
  const int g16 = blockIdx.x, g8 = g16 >> 1, half = g16 & 1;
  const int n0 = blockIdx.y * 256;
  const char* img = (const char*)Tswz + (size_t)g8 * 8 * 32768;

  // stage a 16 KiB half-image: seg in [0,16): cl = seg>>1 (4 KiB/cl in src,
  // 2 KiB/cl in LDS), piece = seg&1. The XOR swizzle is confined to 128B,
  // so the half-slice [half*2048, +2048) of each cl is self-contained.
  #define STAGE(CH, BUF)                                                     \
    {                                                                        \
      const char* src_ = img + (CH) * 32768;                                 \
      _Pragma("unroll")                                                      \
      for (int i_ = 0; i_ < 4; ++i_) {                                       \
        int seg_ = wid * 4 + i_;                                             \
        gld16(src_ + (seg_ >> 1) * 4096 + half * 2048 + (seg_ & 1) * 1024    \
                  + lane * 16,                                               \
              (char*)&Tb[(BUF)][0] + seg_ * 1024);                           \
      }                                                                      \
    }

  STAGE(0, 0);

  f32x16 acc[4];
  #pragma unroll
  for (int rt = 0; rt < 4; ++rt)
    #pragma unroll
    for (int e = 0; e < 16; ++e) acc[rt][e] = 0.f;

  const unsigned char* crow = codes + (size_t)(n0 + rh * 128 + lrow) * CBN;
  const unsigned col_loc = (unsigned)(chh * 32 + lrow);

  __syncthreads();                                  // chunk 0 staged

  #pragma unroll
  for (int ch = 0; ch < 8; ++ch) {
    const int buf = ch & 1;
    unsigned long long qw[4];
    #pragma unroll
    for (int rt = 0; rt < 4; ++rt)
      qw[rt] = *(const unsigned long long*)(crow + (size_t)rt * 32 * CBN + ch * 8);
    if (ch < 7) STAGE(ch + 1, buf ^ 1);
    const unsigned short* tb = (const unsigned short*)&Tb[buf][0];
    __builtin_amdgcn_s_setprio(1);
    #pragma unroll
    for (int cl = 0; cl < 8; ++cl) {
      unsigned uidx = (unsigned)(cl * 1024)          // 1024 u16 per cl (FIX)
                    + ((col_loc * 16 + (unsigned)h * 8)
                       ^ (((col_loc >> 2) & 7u) << 3));
      bf16x8 bv = *(const bf16x8*)(tb + uidx);      // 1 read : 4 MFMA
      #pragma unroll
      for (int rt = 0; rt < 4; ++rt) {
        int c = (int)((qw[rt] >> (8 * cl)) & 255);
        int p = c >> 1;
        unsigned s = 0x3F80u << ((c & 1) << 4);     // bf16(1.0) in right half
        union { unsigned int u[4]; bf16x8 v; } A;
        #pragma unroll
        for (int j = 0; j < 4; ++j) A.u[j] = (p == h * 4 + j) ? s : 0u;
        acc[rt] = __builtin_amdgcn_mfma_f32_32x32x16_bf16(A.v, bv, acc[rt], 0, 0, 0);
      }
    }
    __builtin_amdgcn_s_setprio(0);
    __syncthreads();   // vmcnt drained here -> stage(ch+1) complete
  }

  // epilogue: D layout col=lane&31, row=(reg&3)+8*(reg>>2)+4*(lane>>5)
  const int col = g16 * 64 + chh * 32 + lrow;
  const float bval = bias[col];
  #pragma unroll
  for (int rt = 0; rt < 4; ++rt)
    #pragma unroll
    for (int r = 0; r < 16; ++r) {
      int row = n0 + rh * 128 + rt * 32 + (r & 3) + 8 * (r >> 2) + 4 * h;
      out[(size_t)row * DOUTN + col] = acc[rt][r] + bval;
    }
}

extern "C" void kernel_launch(void* const* d_in, const int* in_sizes, int n_in,
                              void* d_out, int out_size, void* d_ws, size_t ws_size,
                              hipStream_t stream) {
  const float* x    = (const float*)d_in[0];
  const int*   sidx = (const int*)d_in[1];
  const float* sval = (const float*)d_in[2];
  const float* Tg   = (const float*)d_in[3];
  const float* bias = (const float*)d_in[4];
  float* out = (float*)d_out;
  unsigned char* codes = (unsigned char*)d_ws;                       // 1 MiB
  unsigned int*  Tswz  = (unsigned int*)((char*)d_ws + (1 << 20));   // 2 MiB

  prep_k<<<64 + NN / 8, 256, 0, stream>>>(x, sidx, sval, Tg, codes, Tswz);
  maddness_mfma<<<dim3(16, 64), 256, 0, stream>>>(Tswz, bias, codes, out);
}

// Round 6
// 53.014 us; speedup vs baseline: 1.1386x; 1.1386x over previous
//
#include <hip/hip_runtime.h>

#define NN    16384
#define CBN   64
#define SUBV  16
#define KCODE 16
#define DOUTN 1024
#define DEP   4

typedef short bf16x8 __attribute__((ext_vector_type(8)));
typedef float f32x16 __attribute__((ext_vector_type(16)));

static __device__ __forceinline__ unsigned short f2bf(float f) {
  unsigned int u = __float_as_uint(f);
  u += 0x7FFFu + ((u >> 16) & 1u);   // RNE; inputs are normal randn, no NaN/Inf
  return (unsigned short)(u >> 16);
}

// global -> LDS direct copy, 16B/lane. LDS dest wave-uniform (HW adds lane*16).
static __device__ __forceinline__ void gld16(const void* g, void* l) {
  __builtin_amdgcn_global_load_lds(
      (const __attribute__((address_space(1))) unsigned int*)g,
      (__attribute__((address_space(3))) unsigned int*)(uintptr_t)l, 16, 0, 0);
}

// ---------------- kernel 1: table convert/swizzle + encode (fused) ----------
// blocks [0,64): build Tswz (bf16, pre-swizzled 32 KiB images) — scheduled
// FIRST so they overlap encode instead of tailing it.
// blocks [64, 64+2048): encode 8 rows each -> codes[n][c] (u8, n-major).
__global__ __launch_bounds__(256) void prep_k(
    const float* __restrict__ x, const int* __restrict__ split_idxs,
    const float* __restrict__ split_vals, const float* __restrict__ Tg,
    unsigned char* __restrict__ codes, unsigned int* __restrict__ Tswz) {
  const int t = threadIdx.x;

  if (blockIdx.x < 64) {
    // ---- convert + swizzle: one block per (g8, ch) image ----
    const int img = blockIdx.x;                   // = g8*8 + ch
    const int g = img >> 3, ch = img & 7;
    unsigned int* dst = Tswz + (size_t)img * 8192; // 8192 u32 = 32 KiB image
    const int colq = t & 31, kp = (t >> 5) & 7;
    #pragma unroll
    for (int cl = 0; cl < 8; ++cl) {
      const float* g0 = Tg + ((size_t)((ch * 8 + cl) * KCODE + 2 * kp)) * DOUTN
                        + g * 128 + colq * 4;
      float4 r0 = *(const float4*)g0;             // k=2kp   (coalesced)
      float4 r1 = *(const float4*)(g0 + DOUTN);   // k=2kp+1
      unsigned int pk[4] = {
        f2bf(r0.x) | ((unsigned int)f2bf(r1.x) << 16),
        f2bf(r0.y) | ((unsigned int)f2bf(r1.y) << 16),
        f2bf(r0.z) | ((unsigned int)f2bf(r1.z) << 16),
        f2bf(r0.w) | ((unsigned int)f2bf(r1.w) << 16)};
      unsigned key = (unsigned)(colq & 7) << 2;   // XOR on u32-idx bits[4:2]
      #pragma unroll
      for (int j = 0; j < 4; ++j)
        dst[cl * 1024 + ((((unsigned)(colq * 4 + j)) * 8 + (unsigned)kp) ^ key)]
            = pk[j];
    }
    return;
  }

  // ---- encode ----
  // xs = 32 KiB; bank spread via size-neutral XOR swizzle s^((c>>1)&15).
  __shared__ float xs[8][SUBV * CBN];
  __shared__ int   sidxT[DEP * CBN];               // [d][c]
  __shared__ float svalT[DEP * (KCODE / 2) * CBN]; // [d][e][c]
  if (t < DEP * CBN) {
    int d = t >> 6, c = t & 63;
    sidxT[t] = split_idxs[c * DEP + d];
  }
  for (int i = t; i < DEP * (KCODE / 2) * CBN; i += 256) {
    int c = i & 63, de = i >> 6, d = de >> 3, e = de & 7;
    svalT[i] = split_vals[(c * DEP + d) * (KCODE / 2) + e];
  }
  const int n0 = (blockIdx.x - 64) * 8;
  const float4* xg = (const float4*)(x + (size_t)n0 * DOUTN);
  #pragma unroll
  for (int i = 0; i < 8; ++i) {                    // 8 rows * 256 float4/row
    int li = t + i * 256;
    int r = li >> 8, cpos = li & 255;
    float4 v = xg[r * 256 + cpos];
    int c = cpos >> 2, s0 = (cpos & 3) * 4, m = (c >> 1) & 15;
    float* row = &xs[r][c * SUBV];
    row[(s0 + 0) ^ m] = v.x; row[(s0 + 1) ^ m] = v.y;
    row[(s0 + 2) ^ m] = v.z; row[(s0 + 3) ^ m] = v.w;
  }
  __syncthreads();
  const int c = t & 63, rg = t >> 6, m = (c >> 1) & 15;
  #pragma unroll
  for (int i = 0; i < 2; ++i) {
    int nl = rg * 2 + i;
    int e = 0;
    #pragma unroll
    for (int d = 0; d < DEP; ++d) {
      float xv = xs[nl][c * SUBV + (sidxT[d * 64 + c] ^ m)];
      float th = svalT[(d * 8 + e) * 64 + c];
      e = 2 * e + (xv > th ? 1 : 0);
    }
    codes[(size_t)(n0 + nl) * CBN + c] = (unsigned char)e;
  }
}

// ---------------- kernel 2: one-hot MFMA gather-accumulate ----------------
// grid (16 colgroups of 64, 64 rowgroups) = 1024 blocks; 256 thr = 4 waves;
// __launch_bounds__(256,4) -> 4 blocks/CU = EXACTLY one occupancy round
// (R5's (256,3) left a 1-block/CU tail round = half the runtime idle).
// Wave wid = row-quad: 64 rows x 64 cols (rt=2 x ct=2). vs R5's 128x32 this
// HALVES one-hot A-builds per thread (VALU was top pipe at 52%) and removes
// the cross-wave duplicate A work; each A feeds 2 MFMA, each B-read 2 MFMA.
__global__ __launch_bounds__(256, 4) void maddness_mfma(
    const unsigned int* __restrict__ Tswz, const float* __restrict__ bias,
    const unsigned char* __restrict__ codes, float* __restrict__ out) {
  __shared__ __align__(16) unsigned int Tb[2][4096];   // 2 x 16 KiB

  const int t = threadIdx.x;
  const int wid = t >> 6, lane = t & 63, lrow = lane & 31, h = lane >> 5;
  const int g16 = blockIdx.x, g8 = g16 >> 1, half = g16 & 1;
  const int n0 = blockIdx.y * 256;
  const char* img = (const char*)Tswz + (size_t)g8 * 8 * 32768;

  // stage a 16 KiB half-image: seg in [0,16): cl = seg>>1 (4 KiB/cl in src,
  // 2 KiB/cl in LDS), piece = seg&1. XOR swizzle is confined to 128B, so the
  // half-slice [half*2048, +2048) of each cl is self-contained.
  #define STAGE(CH, BUF)                                                     \
    {                                                                        \
      const char* src_ = img + (CH) * 32768;                                 \
      _Pragma("unroll")                                                      \
      for (int i_ = 0; i_ < 4; ++i_) {                                       \
        int seg_ = wid * 4 + i_;                                             \
        gld16(src_ + (seg_ >> 1) * 4096 + half * 2048 + (seg_ & 1) * 1024    \
                  + lane * 16,                                               \
              (char*)&Tb[(BUF)][0] + seg_ * 1024);                           \
      }                                                                      \
    }

  STAGE(0, 0);

  f32x16 acc[2][2];
  #pragma unroll
  for (int rt = 0; rt < 2; ++rt)
    #pragma unroll
    for (int ct = 0; ct < 2; ++ct)
      #pragma unroll
      for (int e = 0; e < 16; ++e) acc[rt][ct][e] = 0.f;

  const unsigned char* crow = codes + (size_t)(n0 + wid * 64 + lrow) * CBN;

  __syncthreads();                                  // chunk 0 staged

  #pragma unroll
  for (int ch = 0; ch < 8; ++ch) {
    const int buf = ch & 1;
    unsigned long long qw[2];
    #pragma unroll
    for (int rt = 0; rt < 2; ++rt)
      qw[rt] = *(const unsigned long long*)(crow + (size_t)rt * 32 * CBN + ch * 8);
    if (ch < 7) STAGE(ch + 1, buf ^ 1);
    const unsigned short* tb = (const unsigned short*)&Tb[buf][0];
    __builtin_amdgcn_s_setprio(1);
    #pragma unroll
    for (int cl = 0; cl < 8; ++cl) {
      bf16x8 bv[2];
      #pragma unroll
      for (int ct = 0; ct < 2; ++ct) {
        unsigned col_loc = (unsigned)(ct * 32 + lrow);
        unsigned uidx = (unsigned)(cl * 1024)        // 1024 u16 per cl
                      + ((col_loc * 16 + (unsigned)h * 8)
                         ^ (((col_loc >> 2) & 7u) << 3));
        bv[ct] = *(const bf16x8*)(tb + uidx);
      }
      #pragma unroll
      for (int rt = 0; rt < 2; ++rt) {
        int c = (int)((qw[rt] >> (8 * cl)) & 255);
        int p = c >> 1;
        unsigned s = 0x3F80u << ((c & 1) << 4);     // bf16(1.0) in right half
        union { unsigned int u[4]; bf16x8 v; } A;
        #pragma unroll
        for (int j = 0; j < 4; ++j) A.u[j] = (p == h * 4 + j) ? s : 0u;
        acc[rt][0] = __builtin_amdgcn_mfma_f32_32x32x16_bf16(A.v, bv[0], acc[rt][0], 0, 0, 0);
        acc[rt][1] = __builtin_amdgcn_mfma_f32_32x32x16_bf16(A.v, bv[1], acc[rt][1], 0, 0, 0);
      }
    }
    __builtin_amdgcn_s_setprio(0);
    __syncthreads();   // vmcnt drained here -> stage(ch+1) complete
  }

  // epilogue: D layout col=lane&31, row=(reg&3)+8*(reg>>2)+4*(lane>>5)
  #pragma unroll
  for (int ct = 0; ct < 2; ++ct) {
    const int col = g16 * 64 + ct * 32 + lrow;
    const float bval = bias[col];
    #pragma unroll
    for (int rt = 0; rt < 2; ++rt)
      #pragma unroll
      for (int r = 0; r < 16; ++r) {
        int row = n0 + wid * 64 + rt * 32 + (r & 3) + 8 * (r >> 2) + 4 * h;
        out[(size_t)row * DOUTN + col] = acc[rt][ct][r] + bval;
      }
  }
}

extern "C" void kernel_launch(void* const* d_in, const int* in_sizes, int n_in,
                              void* d_out, int out_size, void* d_ws, size_t ws_size,
                              hipStream_t stream) {
  const float* x    = (const float*)d_in[0];
  const int*   sidx = (const int*)d_in[1];
  const float* sval = (const float*)d_in[2];
  const float* Tg   = (const float*)d_in[3];
  const float* bias = (const float*)d_in[4];
  float* out = (float*)d_out;
  unsigned char* codes = (unsigned char*)d_ws;                       // 1 MiB
  unsigned int*  Tswz  = (unsigned int*)((char*)d_ws + (1 << 20));   // 2 MiB

  prep_k<<<64 + NN / 8, 256, 0, stream>>>(x, sidx, sval, Tg, codes, Tswz);
  maddness_mfma<<<dim3(16, 64), 256, 0, stream>>>(Tswz, bias, codes, out);
}

// Round 7
// 52.823 us; speedup vs baseline: 1.1427x; 1.0036x over previous
//
#include <hip/hip_runtime.h>

#define NN    16384
#define CBN   64
#define SUBV  16
#define KCODE 16
#define DOUTN 1024
#define DEP   4

typedef short bf16x8 __attribute__((ext_vector_type(8)));
typedef float f32x16 __attribute__((ext_vector_type(16)));

static __device__ __forceinline__ unsigned short f2bf(float f) {
  unsigned int u = __float_as_uint(f);
  u += 0x7FFFu + ((u >> 16) & 1u);   // RNE; inputs are normal randn, no NaN/Inf
  return (unsigned short)(u >> 16);
}

// global -> LDS direct copy, 16B/lane. LDS dest wave-uniform (HW adds lane*16).
static __device__ __forceinline__ void gld16(const void* g, void* l) {
  __builtin_amdgcn_global_load_lds(
      (const __attribute__((address_space(1))) unsigned int*)g,
      (__attribute__((address_space(3))) unsigned int*)(uintptr_t)l, 16, 0, 0);
}

// ---------------- kernel 1: table convert/swizzle + encode (fused) ----------
// blocks [0,64): build Tswz (bf16, pre-swizzled images) — first, so they
// overlap encode. blocks [64, 64+2048): encode 8 rows -> codes[n][c] u8.
__global__ __launch_bounds__(256) void prep_k(
    const float* __restrict__ x, const int* __restrict__ split_idxs,
    const float* __restrict__ split_vals, const float* __restrict__ Tg,
    unsigned char* __restrict__ codes, unsigned int* __restrict__ Tswz) {
  const int t = threadIdx.x;

  if (blockIdx.x < 64) {
    // ---- convert + swizzle: one block per (g8, ch) image ----
    const int img = blockIdx.x;                   // = g8*8 + ch
    const int g = img >> 3, ch = img & 7;
    unsigned int* dst = Tswz + (size_t)img * 8192; // 8192 u32 = 32 KiB image
    const int colq = t & 31, kp = (t >> 5) & 7;
    #pragma unroll
    for (int cl = 0; cl < 8; ++cl) {
      const float* g0 = Tg + ((size_t)((ch * 8 + cl) * KCODE + 2 * kp)) * DOUTN
                        + g * 128 + colq * 4;
      float4 r0 = *(const float4*)g0;             // k=2kp   (coalesced)
      float4 r1 = *(const float4*)(g0 + DOUTN);   // k=2kp+1
      unsigned int pk[4] = {
        f2bf(r0.x) | ((unsigned int)f2bf(r1.x) << 16),
        f2bf(r0.y) | ((unsigned int)f2bf(r1.y) << 16),
        f2bf(r0.z) | ((unsigned int)f2bf(r1.z) << 16),
        f2bf(r0.w) | ((unsigned int)f2bf(r1.w) << 16)};
      unsigned key = (unsigned)(colq & 7) << 2;   // XOR on u32-idx bits[4:2]
      #pragma unroll
      for (int j = 0; j < 4; ++j)
        dst[cl * 1024 + ((((unsigned)(colq * 4 + j)) * 8 + (unsigned)kp) ^ key)]
            = pk[j];
    }
    return;
  }

  // ---- encode ----
  // Quad-granular XOR swizzle (quad q stored at q^(c&3)): keeps ds_write_b128
  // (R6's element-granular swizzle forced 32 scalar ds_write_b32/thread) while
  // still spreading banks for the random-element reads.
  __shared__ __align__(16) float xs[8][SUBV * CBN];
  __shared__ int   sidxT[DEP * CBN];               // [d][c]
  __shared__ float svalT[DEP * (KCODE / 2) * CBN]; // [d][e][c]
  if (t < DEP * CBN) {
    int d = t >> 6, c = t & 63;
    sidxT[t] = split_idxs[c * DEP + d];
  }
  for (int i = t; i < DEP * (KCODE / 2) * CBN; i += 256) {
    int c = i & 63, de = i >> 6, d = de >> 3, e = de & 7;
    svalT[i] = split_vals[(c * DEP + d) * (KCODE / 2) + e];
  }
  const int n0 = (blockIdx.x - 64) * 8;
  const float4* xg = (const float4*)(x + (size_t)n0 * DOUTN);
  #pragma unroll
  for (int i = 0; i < 8; ++i) {                    // 8 rows * 256 float4/row
    int li = t + i * 256;
    int r = li >> 8, cpos = li & 255;
    float4 v = xg[r * 256 + cpos];
    int c = cpos >> 2, q = cpos & 3;
    *(float4*)&xs[r][c * SUBV + ((q ^ (c & 3)) << 2)] = v;
  }
  __syncthreads();
  const int c = t & 63, rg = t >> 6;
  #pragma unroll
  for (int i = 0; i < 2; ++i) {
    int nl = rg * 2 + i;
    int e = 0;
    #pragma unroll
    for (int d = 0; d < DEP; ++d) {
      int si = sidxT[d * 64 + c];
      float xv = xs[nl][c * SUBV + (((si >> 2) ^ (c & 3)) << 2) + (si & 3)];
      float th = svalT[(d * 8 + e) * 64 + c];
      e = 2 * e + (xv > th ? 1 : 0);
    }
    codes[(size_t)(n0 + nl) * CBN + c] = (unsigned char)e;
  }
}

// ---------------- kernel 2: one-hot MFMA gather-accumulate ----------------
// grid (16 colgroups of 64, 16 rowgroups of 1024) = 256 blocks = 1 per CU.
// 1024 thr = 16 waves; wave wid = 64 rows x 64 cols (rt=2 x ct=2; same
// proven per-wave compute as R6). The ENTIRE colgroup table (8 chunks x
// 16 KiB = 128 KiB) is staged into LDS ONCE -> one barrier total, then waves
// free-run: no double-buffer, no per-chunk vmcnt(0) barrier drains, and the
// L2 table traffic drops 128 MB -> 32 MB. Codes prefetched one chunk ahead.
__global__ __launch_bounds__(1024, 4) void maddness_mfma(
    const unsigned int* __restrict__ Tswz, const float* __restrict__ bias,
    const unsigned char* __restrict__ codes, float* __restrict__ out) {
  __shared__ __align__(16) unsigned int Tb[32768];   // 128 KiB, all 8 chunks

  const int t = threadIdx.x;
  const int wid = t >> 6, lane = t & 63, lrow = lane & 31, h = lane >> 5;
  const int g16 = blockIdx.x, g8 = g16 >> 1, half = g16 & 1;
  const int n0 = blockIdx.y * 1024;
  const char* img = (const char*)Tswz + (size_t)g8 * 8 * 32768;

  // stage all 8 chunk half-images: 128 segs of 1024 B; wave stages 8.
  // seg gs: ch = gs>>4, s16 = gs&15, cl = s16>>1, piece = s16&1.
  // XOR swizzle is confined to 128 B, so the 2 KiB half-slice per cl
  // [half*2048, +2048) is self-contained (same mapping as R6, verified).
  #pragma unroll
  for (int i = 0; i < 8; ++i) {
    int gs = wid * 8 + i;
    int ch = gs >> 4, s16 = gs & 15, cl = s16 >> 1, pc = s16 & 1;
    gld16(img + ch * 32768 + cl * 4096 + half * 2048 + pc * 1024 + lane * 16,
          (char*)Tb + gs * 1024);
  }

  f32x16 acc[2][2];
  #pragma unroll
  for (int rt = 0; rt < 2; ++rt)
    #pragma unroll
    for (int ct = 0; ct < 2; ++ct)
      #pragma unroll
      for (int e = 0; e < 16; ++e) acc[rt][ct][e] = 0.f;

  const unsigned char* crow = codes + (size_t)(n0 + wid * 64 + lrow) * CBN;
  unsigned long long qwA[2], qwB[2];
  qwA[0] = *(const unsigned long long*)(crow);
  qwA[1] = *(const unsigned long long*)(crow + 32 * CBN);

  __syncthreads();                                  // the ONLY barrier

  #pragma unroll
  for (int ch = 0; ch < 8; ++ch) {
    if (ch < 7) {                                   // prefetch next codes
      qwB[0] = *(const unsigned long long*)(crow + (ch + 1) * 8);
      qwB[1] = *(const unsigned long long*)(crow + 32 * CBN + (ch + 1) * 8);
    }
    const unsigned short* tb = (const unsigned short*)Tb + ch * 8192;
    __builtin_amdgcn_s_setprio(1);
    #pragma unroll
    for (int cl = 0; cl < 8; ++cl) {
      bf16x8 bv[2];
      #pragma unroll
      for (int ct = 0; ct < 2; ++ct) {
        unsigned col_loc = (unsigned)(ct * 32 + lrow);
        unsigned uidx = (unsigned)(cl * 1024)        // 1024 u16 per cl
                      + ((col_loc * 16 + (unsigned)h * 8)
                         ^ (((col_loc >> 2) & 7u) << 3));
        bv[ct] = *(const bf16x8*)(tb + uidx);
      }
      #pragma unroll
      for (int rt = 0; rt < 2; ++rt) {
        int c = (int)((qwA[rt] >> (8 * cl)) & 255);
        int p = c >> 1;
        unsigned s = 0x3F80u << ((c & 1) << 4);     // bf16(1.0) in right half
        union { unsigned int u[4]; bf16x8 v; } A;
        #pragma unroll
        for (int j = 0; j < 4; ++j) A.u[j] = (p == h * 4 + j) ? s : 0u;
        acc[rt][0] = __builtin_amdgcn_mfma_f32_32x32x16_bf16(A.v, bv[0], acc[rt][0], 0, 0, 0);
        acc[rt][1] = __builtin_amdgcn_mfma_f32_32x32x16_bf16(A.v, bv[1], acc[rt][1], 0, 0, 0);
      }
    }
    __builtin_amdgcn_s_setprio(0);
    qwA[0] = qwB[0]; qwA[1] = qwB[1];
  }

  // epilogue: D layout col=lane&31, row=(reg&3)+8*(reg>>2)+4*(lane>>5)
  #pragma unroll
  for (int ct = 0; ct < 2; ++ct) {
    const int col = g16 * 64 + ct * 32 + lrow;
    const float bval = bias[col];
    #pragma unroll
    for (int rt = 0; rt < 2; ++rt)
      #pragma unroll
      for (int r = 0; r < 16; ++r) {
        int row = n0 + wid * 64 + rt * 32 + (r & 3) + 8 * (r >> 2) + 4 * h;
        out[(size_t)row * DOUTN + col] = acc[rt][ct][r] + bval;
      }
  }
}

extern "C" void kernel_launch(void* const* d_in, const int* in_sizes, int n_in,
                              void* d_out, int out_size, void* d_ws, size_t ws_size,
                              hipStream_t stream) {
  const float* x    = (const float*)d_in[0];
  const int*   sidx = (const int*)d_in[1];
  const float* sval = (const float*)d_in[2];
  const float* Tg   = (const float*)d_in[3];
  const float* bias = (const float*)d_in[4];
  float* out = (float*)d_out;
  unsigned char* codes = (unsigned char*)d_ws;                       // 1 MiB
  unsigned int*  Tswz  = (unsigned int*)((char*)d_ws + (1 << 20));   // 2 MiB

  prep_k<<<64 + NN / 8, 256, 0, stream>>>(x, sidx, sval, Tg, codes, Tswz);
  maddness_mfma<<<dim3(16, 16), 1024, 0, stream>>>(Tswz, bias, codes, out);
}